// Round 2
// baseline (336.369 us; speedup 1.0000x reference)
//
#include <hip/hip_runtime.h>
#include <hip/hip_bf16.h>

#define N_NODES 100000
#define N_EDGES 1600000
#define HDIM    128
#define KCH     4                  // K chunks of 32 (K = 128)
#define NUM_CARDS 110
#define NTILES  (N_NODES / 16)     // 6250 exactly
#define GEMM_BLOCKS 1024

#define NB      196                // node buckets: dst >> 9
#define MAXB    10240              // slack per bucket (avg 8192)
#define PT      4096               // edges per partition block
#define PEPT    16                 // edges per thread in partition

typedef __attribute__((ext_vector_type(8))) short bfrag;   // 8 bf16 = 4 VGPRs
typedef __attribute__((ext_vector_type(4))) float ffrag;   // 4 f32 acc
typedef __attribute__((ext_vector_type(2))) float f32x2;

__device__ inline unsigned short f2bf(float f) {
    __hip_bfloat16 h = __float2bfloat16(f);
    unsigned short u; __builtin_memcpy(&u, &h, 2); return u;
}
__device__ inline float bf_lo(unsigned int u) {
    unsigned int v = u << 16; float f; __builtin_memcpy(&f, &v, 4); return f;
}
__device__ inline float bf_hi(unsigned int u) {
    unsigned int v = u & 0xffff0000u; float f; __builtin_memcpy(&f, &v, 4); return f;
}

// ---------------- CSR build: bucketed counting sort ----------------
// pack: (dst & 511) << 17 | src   (src < 2^17)

__global__ __launch_bounds__(256) void k_partition(
    const int* __restrict__ src, const int* __restrict__ dst,
    int* __restrict__ bucket_cursor, unsigned int* __restrict__ part) {
    __shared__ int hist[NB];
    __shared__ int hcur[NB];
    const int t = threadIdx.x;
    const int base = blockIdx.x * PT;
    for (int i = t; i < NB; i += 256) hist[i] = 0;
    __syncthreads();
#pragma unroll
    for (int i = 0; i < PEPT; i++) {
        int e = base + i * 256 + t;
        if (e < N_EDGES) atomicAdd(&hist[dst[e] >> 9], 1);
    }
    __syncthreads();
    for (int b = t; b < NB; b += 256) {
        int h = hist[b];
        hcur[b] = h ? atomicAdd(&bucket_cursor[b], h) : 0;
    }
    __syncthreads();
#pragma unroll
    for (int i = 0; i < PEPT; i++) {
        int e = base + i * 256 + t;
        if (e < N_EDGES) {
            int d = dst[e];
            int b = d >> 9;
            int r = atomicAdd(&hcur[b], 1);
            if (r < MAXB)
                part[(size_t)b * MAXB + r] =
                    ((unsigned int)(d & 511) << 17) | (unsigned int)src[e];
        }
    }
}

// fixed-stride csr layout: bucket b owns csr_src[b*MAXB .. b*MAXB+cnt)
__global__ __launch_bounds__(256) void k_bucket(
    const unsigned int* __restrict__ part, const int* __restrict__ bucket_cursor,
    int* __restrict__ row_off, int* __restrict__ deg, float* __restrict__ deg_inv,
    int* __restrict__ csr_src) {
    __shared__ int degl[512];
    __shared__ int offl[512];
    __shared__ int curl[512];
    __shared__ int stmp[256];
    const int t = threadIdx.x;
    const int b = blockIdx.x;
    const int n0 = b << 9;
    const int nb = min(512, N_NODES - n0);
    const int cnt = min(bucket_cursor[b], MAXB);
    const int row0 = b * MAXB;
    const unsigned int* pb = &part[(size_t)b * MAXB];

    degl[t] = 0; degl[t + 256] = 0;
    __syncthreads();
    for (int i = t; i < cnt; i += 256)
        atomicAdd(&degl[pb[i] >> 17], 1);
    __syncthreads();
    const int a0 = degl[2 * t], a1 = degl[2 * t + 1];
    stmp[t] = a0 + a1;
    __syncthreads();
    for (int off = 1; off < 256; off <<= 1) {
        int x = (t >= off) ? stmp[t - off] : 0;
        __syncthreads();
        stmp[t] += x;
        __syncthreads();
    }
    const int excl = stmp[t] - (a0 + a1);
    offl[2 * t] = excl;          curl[2 * t] = excl;
    offl[2 * t + 1] = excl + a0; curl[2 * t + 1] = excl + a0;
    __syncthreads();
    for (int i = t; i < nb; i += 256) {
        int n = n0 + i;
        int d = degl[i];
        row_off[n] = row0 + offl[i];
        deg[n] = d;
        deg_inv[n] = (d > 0) ? 1.0f / (float)d : 0.0f;
    }
    for (int i = t; i < cnt; i += 256) {
        unsigned int pk = pb[i];
        int r = atomicAdd(&curl[pk >> 17], 1);
        csr_src[row0 + r] = (int)(pk & 0x1FFFFu);
    }
}

// ---------------- prep: weights -> bf16 concat layouts ----------------

__global__ void k_prep_w(const float* __restrict__ Wl1, const float* __restrict__ Wr1,
                         const float* __restrict__ bl1, const float* __restrict__ br1,
                         const float* __restrict__ Wl2, const float* __restrict__ Wr2,
                         const float* __restrict__ bl2, const float* __restrict__ br2,
                         const float* __restrict__ Wo,  const float* __restrict__ bo,
                         unsigned short* __restrict__ W1, unsigned short* __restrict__ W2,
                         unsigned short* __restrict__ Wob,
                         float* __restrict__ bias1, float* __restrict__ bias2,
                         float* __restrict__ biaso, float* __restrict__ wcard1) {
    const int j = blockIdx.x;   // 0..255
    const int k = threadIdx.x;  // 0..127
    const float* s1 = (j < 128) ? &Wl1[(size_t)j * 129] : &Wr1[(size_t)(j - 128) * 129];
    W1[(size_t)j * HDIM + k] = f2bf(s1[k]);
    const float* s2 = (j < 128) ? &Wl2[(size_t)j * HDIM] : &Wr2[(size_t)(j - 128) * HDIM];
    W2[(size_t)j * HDIM + k] = f2bf(s2[k]);
    if (j < 112)
        Wob[(size_t)j * HDIM + k] = (j < NUM_CARDS) ? f2bf(Wo[(size_t)j * HDIM + k])
                                                    : (unsigned short)0;
    if (k == 0) {
        wcard1[j] = s1[HDIM];
        bias1[j] = (j < 128) ? 0.f : (bl1[j - 128] + br1[j - 128]);
        bias2[j] = (j < 128) ? 0.f : (bl2[j - 128] + br2[j - 128]);
        if (j < 112) biaso[j] = (j < NUM_CARDS) ? bo[j] : 0.f;
    }
}

// ---------------- dual GEMM: Gq (fp8 e4m3) + Rb (bf16) ----------------
// Waves 0,1 own G units (fp8 out); waves 2,3 own R units (bf16 out).
// R1: software-pipelined tile loop. Next-tile A-fragments are loaded into
// "n" buffers while the current tile's MFMAs+stores run; vmcnt retires in
// order so waiting on cur never drains the in-flight nxt loads.

__global__ __launch_bounds__(256) void k_gemm_dual(
    const unsigned short* __restrict__ Ab, const float* __restrict__ Af,
    const int* __restrict__ cards,
    const unsigned short* __restrict__ W,
    const float* __restrict__ bias, const float* __restrict__ wcard,
    unsigned char* __restrict__ Gq, unsigned short* __restrict__ Rb,
    int layer1) {
    const int wave = threadIdx.x >> 6;
    const int lane = threadIdx.x & 63;
    const int m16 = lane & 15;
    const int quad = lane >> 4;
    const int u0 = wave * 4;
    const bool isG = (wave < 2);

    bfrag wf[4][KCH];
    float bs[4][4], wc[4][4];
#pragma unroll
    for (int u = 0; u < 4; u++) {
        const int j = (u0 + u) * 16 + m16;
#pragma unroll
        for (int c = 0; c < KCH; c++)
            wf[u][c] = *(const bfrag*)&W[(size_t)j * HDIM + c * 32 + quad * 8];
#pragma unroll
        for (int r = 0; r < 4; r++) {
            const int jj = (u0 + u) * 16 + quad * 4 + r;
            bs[u][r] = bias[jj];
            wc[u][r] = layer1 ? wcard[jj] : 0.f;
        }
    }

    // pipeline buffers (next tile)
    float4 nA[KCH][2];          // layer1 raw f32
    bfrag  nB[KCH];             // layer2 bf16
    float  cvn = 0.f;

    int tile = blockIdx.x;
    if (tile < NTILES) {
        const int node = tile * 16 + m16;
        if (layer1) {
#pragma unroll
            for (int c = 0; c < KCH; c++) {
                nA[c][0] = *(const float4*)&Af[(size_t)node * HDIM + c * 32 + quad * 8];
                nA[c][1] = *(const float4*)&Af[(size_t)node * HDIM + c * 32 + quad * 8 + 4];
            }
            cvn = (float)cards[node];
        } else {
#pragma unroll
            for (int c = 0; c < KCH; c++)
                nB[c] = *(const bfrag*)&Ab[(size_t)node * HDIM + c * 32 + quad * 8];
        }
    }

    for (; tile < NTILES; tile += GEMM_BLOCKS) {
        // consume next -> cur (vmcnt wait lands here, for loads issued a
        // full iteration ago)
        bfrag hf[KCH];
        const float cv = cvn;
        if (layer1) {
#pragma unroll
            for (int c = 0; c < KCH; c++) {
                const float4 p0 = nA[c][0];
                const float4 p1 = nA[c][1];
                bfrag h;
                h[0] = (short)f2bf(p0.x); h[1] = (short)f2bf(p0.y);
                h[2] = (short)f2bf(p0.z); h[3] = (short)f2bf(p0.w);
                h[4] = (short)f2bf(p1.x); h[5] = (short)f2bf(p1.y);
                h[6] = (short)f2bf(p1.z); h[7] = (short)f2bf(p1.w);
                hf[c] = h;
            }
        } else {
#pragma unroll
            for (int c = 0; c < KCH; c++)
                hf[c] = nB[c];
        }

        // issue next tile's loads (stay in flight across MFMA+store)
        const int tn = tile + GEMM_BLOCKS;
        if (tn < NTILES) {
            const int node = tn * 16 + m16;
            if (layer1) {
#pragma unroll
                for (int c = 0; c < KCH; c++) {
                    nA[c][0] = *(const float4*)&Af[(size_t)node * HDIM + c * 32 + quad * 8];
                    nA[c][1] = *(const float4*)&Af[(size_t)node * HDIM + c * 32 + quad * 8 + 4];
                }
                cvn = (float)cards[node];
            } else {
#pragma unroll
                for (int c = 0; c < KCH; c++)
                    nB[c] = *(const bfrag*)&Ab[(size_t)node * HDIM + c * 32 + quad * 8];
            }
        }

        // compute + store current tile
        const int node = tile * 16 + m16;
#pragma unroll
        for (int u = 0; u < 4; u++) {
            ffrag acc = {0.f, 0.f, 0.f, 0.f};
#pragma unroll
            for (int c = 0; c < KCH; c++)
                acc = __builtin_amdgcn_mfma_f32_16x16x32_bf16(wf[u][c], hf[c], acc, 0, 0, 0);
            float v[4];
#pragma unroll
            for (int r = 0; r < 4; r++)
                v[r] = acc[r] + bs[u][r] + cv * wc[u][r];
            if (isG) {
                int pk = __builtin_amdgcn_cvt_pk_fp8_f32(v[0], v[1], 0, false);
                pk = __builtin_amdgcn_cvt_pk_fp8_f32(v[2], v[3], pk, true);
                *(unsigned int*)&Gq[(size_t)node * HDIM + (u0 + u) * 16 + quad * 4] =
                    (unsigned int)pk;
            } else {
                unsigned short o[4];
#pragma unroll
                for (int r = 0; r < 4; r++) o[r] = f2bf(v[r]);
                uint2 p = {(unsigned int)o[0] | ((unsigned int)o[1] << 16),
                           (unsigned int)o[2] | ((unsigned int)o[3] << 16)};
                *(uint2*)&Rb[(size_t)node * HDIM + (u0 + u - 8) * 16 + quad * 4] = p;
            }
        }
    }
}

// ---------------- aggregate: h' = relu(mean(Gq[src]) + Rb) ----------------
// 8 nodes per wave, 8 lanes per node, each lane privately accumulates 16
// contiguous fp8 features across its node's edge list (no cross-lane
// reduction; all 64 lanes produce output). Edge indices: chunk of 8
// preloaded per group, double-buffered (idxA/idxB), broadcast via full-exec
// __shfl. Gather software-pipelined cur/nxt (vmcnt overlap). Inner loop
// runs to the max degree over the wave's 8 nodes.

__global__ __launch_bounds__(256) void k_agg(
    const unsigned char* __restrict__ Gq, const unsigned short* __restrict__ Rb,
    const int* __restrict__ row_off, const int* __restrict__ deg,
    const float* __restrict__ deg_inv, const int* __restrict__ csr_src,
    unsigned short* __restrict__ outH) {
    const int wave = threadIdx.x >> 6;
    const int lane = threadIdx.x & 63;
    const int g = lane >> 3;        // node slot 0..7 within wave
    const int l = lane & 7;         // feature slice within node
    const int n = (blockIdx.x * 4 + wave) * 8 + g;
    const int start = row_off[n];
    const int d = deg[n];
    const float di = deg_inv[n];
    const int fo = l * 16;          // fp8 byte offset == bf16 element offset

    // wave-uniform max degree over the 8 groups (group id lives in lane bits 3..5)
    int dmax = d;
    dmax = max(dmax, __shfl_xor(dmax, 8, 64));
    dmax = max(dmax, __shfl_xor(dmax, 16, 64));
    dmax = max(dmax, __shfl_xor(dmax, 32, 64));

    // prefetch the R slice (all 64 lanes useful)
    const uint4 rv0 = *(const uint4*)&Rb[(size_t)n * HDIM + fo];
    const uint4 rv1 = *(const uint4*)&Rb[(size_t)n * HDIM + fo + 8];

    f32x2 acc2[8];
#pragma unroll
    for (int i = 0; i < 8; i++) acc2[i] = (f32x2){0.f, 0.f};

    // chunked edge-index prefetch: idxA = chunk c (iters c*8..c*8+7),
    // idxB = chunk c+1. Lane l of group g holds csr_src[start_g + c*8 + l].
    int idxA = (l < d) ? csr_src[start + l] * HDIM : 0;
    int idxB = (8 + l < d) ? csr_src[start + 8 + l] * HDIM : 0;

    uint4 cur = {0u, 0u, 0u, 0u};
    {
        const int off0 = __shfl(idxA, g << 3, 64);        // full-exec shfl
        if (0 < d) cur = *(const uint4*)&Gq[(size_t)(unsigned)off0 + fo];
    }
#define ACC16(Cv)                                                        \
    acc2[0] += __builtin_amdgcn_cvt_pk_f32_fp8((int)(Cv).x, false);      \
    acc2[1] += __builtin_amdgcn_cvt_pk_f32_fp8((int)(Cv).x, true);       \
    acc2[2] += __builtin_amdgcn_cvt_pk_f32_fp8((int)(Cv).y, false);      \
    acc2[3] += __builtin_amdgcn_cvt_pk_f32_fp8((int)(Cv).y, true);       \
    acc2[4] += __builtin_amdgcn_cvt_pk_f32_fp8((int)(Cv).z, false);      \
    acc2[5] += __builtin_amdgcn_cvt_pk_f32_fp8((int)(Cv).z, true);       \
    acc2[6] += __builtin_amdgcn_cvt_pk_f32_fp8((int)(Cv).w, false);      \
    acc2[7] += __builtin_amdgcn_cvt_pk_f32_fp8((int)(Cv).w, true);

    for (int i = 1; i < dmax; i++) {
        const int sl = i & 7;
        if (sl == 0) {               // wave-uniform chunk rotation
            idxA = idxB;
            const int j = i + 8 + l; // base of chunk c+2
            idxB = (j < d) ? csr_src[start + j] * HDIM : 0;
        }
        const int offn = __shfl(idxA, (g << 3) | sl, 64); // full-exec shfl
        uint4 nxt = {0u, 0u, 0u, 0u};
        if (i < d) nxt = *(const uint4*)&Gq[(size_t)(unsigned)offn + fo];
        // consume cur (vmcnt(1): nxt stays in flight)
        ACC16(cur);
        cur = nxt;
    }
    ACC16(cur);
#undef ACC16

    // epilogue: every lane scales its 16 features, adds R, relu, packs, stores
    const float r[16] = {bf_lo(rv0.x), bf_hi(rv0.x), bf_lo(rv0.y), bf_hi(rv0.y),
                         bf_lo(rv0.z), bf_hi(rv0.z), bf_lo(rv0.w), bf_hi(rv0.w),
                         bf_lo(rv1.x), bf_hi(rv1.x), bf_lo(rv1.y), bf_hi(rv1.y),
                         bf_lo(rv1.z), bf_hi(rv1.z), bf_lo(rv1.w), bf_hi(rv1.w)};
    unsigned short o[16];
#pragma unroll
    for (int i = 0; i < 8; i++) {
        o[2 * i]     = f2bf(fmaxf(acc2[i].x * di + r[2 * i], 0.f));
        o[2 * i + 1] = f2bf(fmaxf(acc2[i].y * di + r[2 * i + 1], 0.f));
    }
    uint4 p0, p1;
    p0.x = (unsigned int)o[0] | ((unsigned int)o[1] << 16);
    p0.y = (unsigned int)o[2] | ((unsigned int)o[3] << 16);
    p0.z = (unsigned int)o[4] | ((unsigned int)o[5] << 16);
    p0.w = (unsigned int)o[6] | ((unsigned int)o[7] << 16);
    p1.x = (unsigned int)o[8] | ((unsigned int)o[9] << 16);
    p1.y = (unsigned int)o[10] | ((unsigned int)o[11] << 16);
    p1.z = (unsigned int)o[12] | ((unsigned int)o[13] << 16);
    p1.w = (unsigned int)o[14] | ((unsigned int)o[15] << 16);
    *(uint4*)&outH[(size_t)n * HDIM + fo] = p0;
    *(uint4*)&outH[(size_t)n * HDIM + fo + 8] = p1;
}

// ---------------- logits GEMM, j-major output ----------------
// R1: same software-pipeline as k_gemm_dual.

__global__ __launch_bounds__(256) void k_gemm_logits(
    const unsigned short* __restrict__ A, const unsigned short* __restrict__ W,
    const float* __restrict__ bias, float* __restrict__ out) {
    const int wave = threadIdx.x >> 6;
    const int lane = threadIdx.x & 63;
    const int m16 = lane & 15;
    const int quad = lane >> 4;
    const int u0 = wave * 2;

    bfrag wf[2][KCH];
    float bsj[2];
#pragma unroll
    for (int u = 0; u < 2; u++) {
        const int unit = u0 + u;
        const int j = (unit < 7 ? unit : 0) * 16 + m16;
#pragma unroll
        for (int c = 0; c < KCH; c++)
            wf[u][c] = *(const bfrag*)&W[(size_t)j * HDIM + c * 32 + quad * 8];
        bsj[u] = bias[j];
    }

    bfrag nB[KCH];
    int tile = blockIdx.x;
    if (tile < NTILES) {
        const int nodef = tile * 16 + m16;
#pragma unroll
        for (int c = 0; c < KCH; c++)
            nB[c] = *(const bfrag*)&A[(size_t)nodef * HDIM + c * 32 + quad * 8];
    }

    for (; tile < NTILES; tile += GEMM_BLOCKS) {
        bfrag hf[KCH];
#pragma unroll
        for (int c = 0; c < KCH; c++)
            hf[c] = nB[c];

        const int tn = tile + GEMM_BLOCKS;
        if (tn < NTILES) {
            const int nodef = tn * 16 + m16;
#pragma unroll
            for (int c = 0; c < KCH; c++)
                nB[c] = *(const bfrag*)&A[(size_t)nodef * HDIM + c * 32 + quad * 8];
        }

#pragma unroll
        for (int u = 0; u < 2; u++) {
            const int unit = u0 + u;
            if (unit >= 7) break;
            ffrag acc = {0.f, 0.f, 0.f, 0.f};
#pragma unroll
            for (int c = 0; c < KCH; c++)
                acc = __builtin_amdgcn_mfma_f32_16x16x32_bf16(hf[c], wf[u][c], acc, 0, 0, 0);
            const int j = unit * 16 + m16;
            if (j < NUM_CARDS) {
#pragma unroll
                for (int r = 0; r < 4; r++) {
                    const int node = tile * 16 + quad * 4 + r;
                    out[(size_t)node * NUM_CARDS + j] = acc[r] + bsj[u];
                }
            }
        }
    }
}

// ---------------- launch ----------------

static inline size_t align_up(size_t x, size_t a) { return (x + a - 1) & ~(a - 1); }

extern "C" void kernel_launch(void* const* d_in, const int* in_sizes, int n_in,
                              void* d_out, int out_size, void* d_ws, size_t ws_size,
                              hipStream_t stream) {
    const float* x   = (const float*)d_in[0];
    const float* Wl1 = (const float*)d_in[1];
    const float* bl1 = (const float*)d_in[2];
    const float* Wr1 = (const float*)d_in[3];
    const float* br1 = (const float*)d_in[4];
    const float* Wl2 = (const float*)d_in[5];
    const float* bl2 = (const float*)d_in[6];
    const float* Wr2 = (const float*)d_in[7];
    const float* br2 = (const float*)d_in[8];
    const float* Wo  = (const float*)d_in[9];
    const float* bo  = (const float*)d_in[10];
    const int* edge  = (const int*)d_in[11];
    const int* cards = (const int*)d_in[12];
    float* logits = (float*)d_out;

    const int* e_src = edge;
    const int* e_dst = edge + N_EDGES;

    char* w = (char*)d_ws;
    size_t off = 0;
    int* bucket_cursor = (int*)(w + off); off = align_up(off + 256 * 4, 512);
    unsigned int* part = (unsigned int*)(w + off); off = align_up(off + (size_t)NB * MAXB * 4, 512);
    int* row_off = (int*)(w + off); off = align_up(off + N_NODES * 4, 512);
    int* deg_i   = (int*)(w + off); off = align_up(off + N_NODES * 4, 512);
    float* dinv  = (float*)(w + off); off = align_up(off + N_NODES * 4, 512);
    int* csr_src = (int*)(w + off); off = align_up(off + (size_t)NB * MAXB * 4, 512);
    unsigned char*  Gq   = (unsigned char*)(w + off);  off = align_up(off + (size_t)N_NODES * HDIM, 512);
    unsigned short* Rb   = (unsigned short*)(w + off); off = align_up(off + (size_t)N_NODES * HDIM * 2, 512);
    unsigned short* bufH = (unsigned short*)(w + off); off = align_up(off + (size_t)N_NODES * HDIM * 2, 512);
    unsigned short* W1   = (unsigned short*)(w + off); off = align_up(off + 256 * HDIM * 2, 512);
    unsigned short* W2   = (unsigned short*)(w + off); off = align_up(off + 256 * HDIM * 2, 512);
    unsigned short* Wob  = (unsigned short*)(w + off); off = align_up(off + 112 * HDIM * 2, 512);
    float* bias1  = (float*)(w + off); off = align_up(off + 256 * 4, 512);
    float* bias2  = (float*)(w + off); off = align_up(off + 256 * 4, 512);
    float* biaso  = (float*)(w + off); off = align_up(off + 112 * 4, 512);
    float* wcard1 = (float*)(w + off); off = align_up(off + 256 * 4, 512);
    (void)ws_size; (void)n_in; (void)in_sizes; (void)out_size;

    hipMemsetAsync(bucket_cursor, 0, 256 * 4, stream);
    k_prep_w<<<256, 128, 0, stream>>>(Wl1, Wr1, bl1, br1, Wl2, Wr2, bl2, br2, Wo, bo,
                                      W1, W2, Wob, bias1, bias2, biaso, wcard1);

    const int PBLK = (N_EDGES + PT - 1) / PT;   // 391
    k_partition<<<PBLK, 256, 0, stream>>>(e_src, e_dst, bucket_cursor, part);
    k_bucket<<<NB, 256, 0, stream>>>(part, bucket_cursor,
                                     row_off, deg_i, dinv, csr_src);

    // layer 1 (reads f32 x directly, converts in-register)
    k_gemm_dual<<<GEMM_BLOCKS, 256, 0, stream>>>(nullptr, x, cards, W1, bias1, wcard1, Gq, Rb, 1);
    k_agg<<<N_NODES / 32, 256, 0, stream>>>(Gq, Rb, row_off, deg_i, dinv, csr_src, bufH);
    // layer 2
    k_gemm_dual<<<GEMM_BLOCKS, 256, 0, stream>>>(bufH, nullptr, nullptr, W2, bias2, wcard1, Gq, Rb, 0);
    k_agg<<<N_NODES / 32, 256, 0, stream>>>(Gq, Rb, row_off, deg_i, dinv, csr_src, bufH);
    // output
    k_gemm_logits<<<GEMM_BLOCKS, 256, 0, stream>>>(bufH, Wob, biaso, logits);
}

// Round 3
// 317.384 us; speedup vs baseline: 1.0598x; 1.0598x over previous
//
#include <hip/hip_runtime.h>
#include <hip/hip_bf16.h>

#define N_NODES 100000
#define N_EDGES 1600000
#define HDIM    128
#define KCH     4                  // K chunks of 32 (K = 128)
#define NUM_CARDS 110
#define NTILES  (N_NODES / 16)     // 6250 exactly
#define GEMM_BLOCKS 1024

#define NB      196                // node buckets: dst >> 9
#define MAXB    10240              // slack per bucket (avg 8192)
#define PT      4096               // edges per partition block
#define PEPT    16                 // edges per thread in partition

typedef __attribute__((ext_vector_type(8))) short bfrag;   // 8 bf16 = 4 VGPRs
typedef __attribute__((ext_vector_type(4))) float ffrag;   // 4 f32 acc
typedef __attribute__((ext_vector_type(2))) float f32x2;

__device__ inline unsigned short f2bf(float f) {
    __hip_bfloat16 h = __float2bfloat16(f);
    unsigned short u; __builtin_memcpy(&u, &h, 2); return u;
}
__device__ inline float bf_lo(unsigned int u) {
    unsigned int v = u << 16; float f; __builtin_memcpy(&f, &v, 4); return f;
}
__device__ inline float bf_hi(unsigned int u) {
    unsigned int v = u & 0xffff0000u; float f; __builtin_memcpy(&f, &v, 4); return f;
}

// async global->LDS, 16B per lane; LDS dest = wave-uniform base + lane*16
__device__ inline void gload_lds16(const void* g, void* l) {
    __builtin_amdgcn_global_load_lds(
        (const __attribute__((address_space(1))) unsigned int*)g,
        (__attribute__((address_space(3))) unsigned int*)l, 16, 0, 0);
}

// ---------------- CSR build: bucketed counting sort ----------------
// pack: (dst & 511) << 17 | src   (src < 2^17)

__global__ __launch_bounds__(256) void k_partition(
    const int* __restrict__ src, const int* __restrict__ dst,
    int* __restrict__ bucket_cursor, unsigned int* __restrict__ part) {
    __shared__ int hist[NB];
    __shared__ int hcur[NB];
    const int t = threadIdx.x;
    const int base = blockIdx.x * PT;
    for (int i = t; i < NB; i += 256) hist[i] = 0;
    __syncthreads();
#pragma unroll
    for (int i = 0; i < PEPT; i++) {
        int e = base + i * 256 + t;
        if (e < N_EDGES) atomicAdd(&hist[dst[e] >> 9], 1);
    }
    __syncthreads();
    for (int b = t; b < NB; b += 256) {
        int h = hist[b];
        hcur[b] = h ? atomicAdd(&bucket_cursor[b], h) : 0;
    }
    __syncthreads();
#pragma unroll
    for (int i = 0; i < PEPT; i++) {
        int e = base + i * 256 + t;
        if (e < N_EDGES) {
            int d = dst[e];
            int b = d >> 9;
            int r = atomicAdd(&hcur[b], 1);
            if (r < MAXB)
                part[(size_t)b * MAXB + r] =
                    ((unsigned int)(d & 511) << 17) | (unsigned int)src[e];
        }
    }
}

// fixed-stride csr layout: bucket b owns csr_src[b*MAXB .. b*MAXB+cnt)
__global__ __launch_bounds__(256) void k_bucket(
    const unsigned int* __restrict__ part, const int* __restrict__ bucket_cursor,
    int* __restrict__ row_off, int* __restrict__ deg, float* __restrict__ deg_inv,
    int* __restrict__ csr_src) {
    __shared__ int degl[512];
    __shared__ int offl[512];
    __shared__ int curl[512];
    __shared__ int stmp[256];
    const int t = threadIdx.x;
    const int b = blockIdx.x;
    const int n0 = b << 9;
    const int nb = min(512, N_NODES - n0);
    const int cnt = min(bucket_cursor[b], MAXB);
    const int row0 = b * MAXB;
    const unsigned int* pb = &part[(size_t)b * MAXB];

    degl[t] = 0; degl[t + 256] = 0;
    __syncthreads();
    for (int i = t; i < cnt; i += 256)
        atomicAdd(&degl[pb[i] >> 17], 1);
    __syncthreads();
    const int a0 = degl[2 * t], a1 = degl[2 * t + 1];
    stmp[t] = a0 + a1;
    __syncthreads();
    for (int off = 1; off < 256; off <<= 1) {
        int x = (t >= off) ? stmp[t - off] : 0;
        __syncthreads();
        stmp[t] += x;
        __syncthreads();
    }
    const int excl = stmp[t] - (a0 + a1);
    offl[2 * t] = excl;          curl[2 * t] = excl;
    offl[2 * t + 1] = excl + a0; curl[2 * t + 1] = excl + a0;
    __syncthreads();
    for (int i = t; i < nb; i += 256) {
        int n = n0 + i;
        int d = degl[i];
        row_off[n] = row0 + offl[i];
        deg[n] = d;
        deg_inv[n] = (d > 0) ? 1.0f / (float)d : 0.0f;
    }
    for (int i = t; i < cnt; i += 256) {
        unsigned int pk = pb[i];
        int r = atomicAdd(&curl[pk >> 17], 1);
        csr_src[row0 + r] = (int)(pk & 0x1FFFFu);
    }
}

// ---------------- prep: weights -> bf16 concat layouts ----------------

__global__ void k_prep_w(const float* __restrict__ Wl1, const float* __restrict__ Wr1,
                         const float* __restrict__ bl1, const float* __restrict__ br1,
                         const float* __restrict__ Wl2, const float* __restrict__ Wr2,
                         const float* __restrict__ bl2, const float* __restrict__ br2,
                         const float* __restrict__ Wo,  const float* __restrict__ bo,
                         unsigned short* __restrict__ W1, unsigned short* __restrict__ W2,
                         unsigned short* __restrict__ Wob,
                         float* __restrict__ bias1, float* __restrict__ bias2,
                         float* __restrict__ biaso, float* __restrict__ wcard1) {
    const int j = blockIdx.x;   // 0..255
    const int k = threadIdx.x;  // 0..127
    const float* s1 = (j < 128) ? &Wl1[(size_t)j * 129] : &Wr1[(size_t)(j - 128) * 129];
    W1[(size_t)j * HDIM + k] = f2bf(s1[k]);
    const float* s2 = (j < 128) ? &Wl2[(size_t)j * HDIM] : &Wr2[(size_t)(j - 128) * HDIM];
    W2[(size_t)j * HDIM + k] = f2bf(s2[k]);
    if (j < 112)
        Wob[(size_t)j * HDIM + k] = (j < NUM_CARDS) ? f2bf(Wo[(size_t)j * HDIM + k])
                                                    : (unsigned short)0;
    if (k == 0) {
        wcard1[j] = s1[HDIM];
        bias1[j] = (j < 128) ? 0.f : (bl1[j - 128] + br1[j - 128]);
        bias2[j] = (j < 128) ? 0.f : (bl2[j - 128] + br2[j - 128]);
        if (j < 112) biaso[j] = (j < NUM_CARDS) ? bo[j] : 0.f;
    }
}

// ---------------- dual GEMM: Gq (fp8 e4m3) + Rb (bf16) ----------------
// Waves 0,1 own G units (fp8 out); waves 2,3 own R units (bf16 out).
// R2: block-level LDS double-buffer staging via global_load_lds (16B),
// shared across all 4 waves (kills the 4x redundant A reads and the
// latency exposure). Swizzle per rule #21: linear LDS dest, inverse-
// swizzled per-lane GLOBAL source (involution s ^ ((s>>nodebit)&7) on
// 16B chunk index), swizzled ds_read address. One __syncthreads per
// tile = the vmcnt drain that completes the stage.

__global__ __launch_bounds__(256) void k_gemm_dual(
    const unsigned short* __restrict__ Ab, const float* __restrict__ Af,
    const int* __restrict__ cards,
    const unsigned short* __restrict__ W,
    const float* __restrict__ bias, const float* __restrict__ wcard,
    unsigned char* __restrict__ Gq, unsigned short* __restrict__ Rb,
    int layer1) {
    __shared__ __align__(16) unsigned char smem[16384 + 2048];
    float* bias_l = (float*)(smem + 16384);
    float* wc_l   = (float*)(smem + 16384 + 1024);

    const int tix  = threadIdx.x;
    const int wave = tix >> 6;
    const int lane = tix & 63;
    const int m16  = lane & 15;
    const int quad = lane >> 4;
    const int u0   = wave * 4;
    const bool isG = (wave < 2);
    const int xk   = m16 & 7;

    // weights -> regs (64 VGPR)
    bfrag wf[4][KCH];
#pragma unroll
    for (int u = 0; u < 4; u++) {
        const int j = (u0 + u) * 16 + m16;
#pragma unroll
        for (int c = 0; c < KCH; c++)
            wf[u][c] = *(const bfrag*)&W[(size_t)j * HDIM + c * 32 + quad * 8];
    }

    // bias/wcard -> LDS (frees 32 VGPRs)
    bias_l[tix] = bias[tix];
    wc_l[tix]   = layer1 ? wcard[tix] : 0.f;

    // per-lane swizzled staging source offsets (bytes within tile)
    const int sw1 = (tix ^ ((tix >> 5) & 7)) << 4;   // layer1 f32, node stride 32 chunks
    const int sw2 = (tix ^ ((tix >> 4) & 7)) << 4;   // bf16, node stride 16 chunks
    const int ldsoff = wave << 10;                   // wave*1024 (64 lanes * 16B)

    int tile = blockIdx.x;
    // prologue: stage tile -> buf0
    if (layer1) {
        const unsigned char* g = (const unsigned char*)Af + (size_t)tile * 8192;
        gload_lds16(g + sw1,        smem + ldsoff);
        gload_lds16(g + sw1 + 4096, smem + 4096 + ldsoff);
    } else {
        const unsigned char* g = (const unsigned char*)Ab + (size_t)tile * 4096;
        gload_lds16(g + sw2, smem + ldsoff);
    }
    float cvn = layer1 ? (float)cards[tile * 16 + m16] : 0.f;
    __syncthreads();   // drains vmcnt -> buf0 staged, bias LDS visible

    for (int buf = 0; tile < NTILES; tile += GEMM_BLOCKS, buf ^= 1) {
        const int tn = tile + GEMM_BLOCKS;
        const bool more = (tn < NTILES);
        const float cv = cvn;

        // stage next tile into buf^1 (async; drains at end-of-iter barrier)
        if (more) {
            if (layer1) {
                const unsigned char* g = (const unsigned char*)Af + (size_t)tn * 8192;
                unsigned char* d = smem + (buf ^ 1) * 8192 + ldsoff;
                gload_lds16(g + sw1,        d);
                gload_lds16(g + sw1 + 4096, d + 4096);
                cvn = (float)cards[tn * 16 + m16];
            } else {
                const unsigned char* g = (const unsigned char*)Ab + (size_t)tn * 4096;
                gload_lds16(g + sw2, smem + (buf ^ 1) * 4096 + ldsoff);
            }
        }

        // fragments from LDS (swizzled read addresses)
        const unsigned char* B = smem + buf * (layer1 ? 8192 : 4096);
        bfrag hf[KCH];
        if (layer1) {
#pragma unroll
            for (int c = 0; c < KCH; c++) {
                const int s0 = m16 * 32 + c * 8 + quad * 2;
                const float4 p0 = *(const float4*)(B + (((s0    ) ^ xk) << 4));
                const float4 p1 = *(const float4*)(B + (((s0 + 1) ^ xk) << 4));
                bfrag h;
                h[0] = (short)f2bf(p0.x); h[1] = (short)f2bf(p0.y);
                h[2] = (short)f2bf(p0.z); h[3] = (short)f2bf(p0.w);
                h[4] = (short)f2bf(p1.x); h[5] = (short)f2bf(p1.y);
                h[6] = (short)f2bf(p1.z); h[7] = (short)f2bf(p1.w);
                hf[c] = h;
            }
        } else {
#pragma unroll
            for (int c = 0; c < KCH; c++) {
                const int s = m16 * 16 + c * 4 + quad;
                hf[c] = *(const bfrag*)(B + ((s ^ xk) << 4));
            }
        }

        // compute + store current tile
        const int node = tile * 16 + m16;
#pragma unroll
        for (int u = 0; u < 4; u++) {
            ffrag acc = {0.f, 0.f, 0.f, 0.f};
#pragma unroll
            for (int c = 0; c < KCH; c++)
                acc = __builtin_amdgcn_mfma_f32_16x16x32_bf16(wf[u][c], hf[c], acc, 0, 0, 0);
            const int jj0 = (u0 + u) * 16 + quad * 4;
            const float4 b0 = *(const float4*)&bias_l[jj0];
            const float4 w0 = *(const float4*)&wc_l[jj0];
            float v[4];
            v[0] = acc[0] + b0.x + cv * w0.x;
            v[1] = acc[1] + b0.y + cv * w0.y;
            v[2] = acc[2] + b0.z + cv * w0.z;
            v[3] = acc[3] + b0.w + cv * w0.w;
            if (isG) {
                int pk = __builtin_amdgcn_cvt_pk_fp8_f32(v[0], v[1], 0, false);
                pk = __builtin_amdgcn_cvt_pk_fp8_f32(v[2], v[3], pk, true);
                *(unsigned int*)&Gq[(size_t)node * HDIM + (u0 + u) * 16 + quad * 4] =
                    (unsigned int)pk;
            } else {
                unsigned short o[4];
#pragma unroll
                for (int r = 0; r < 4; r++) o[r] = f2bf(v[r]);
                uint2 p = {(unsigned int)o[0] | ((unsigned int)o[1] << 16),
                           (unsigned int)o[2] | ((unsigned int)o[3] << 16)};
                *(uint2*)&Rb[(size_t)node * HDIM + (u0 + u - 8) * 16 + quad * 4] = p;
            }
        }

        if (more) __syncthreads();  // drain stage of tn; protect buffers
    }
}

// ---------------- aggregate: h' = relu(mean(Gq[src]) + Rb) ----------------
// 8 nodes per wave, 8 lanes per node, each lane privately accumulates 16
// contiguous fp8 features across its node's edge list (no cross-lane
// reduction; all 64 lanes produce output). Edge indices: chunk of 8
// preloaded per group, double-buffered (idxA/idxB), broadcast via full-exec
// __shfl. Gather software-pipelined cur/nxt (vmcnt overlap). Inner loop
// runs to the max degree over the wave's 8 nodes.

__global__ __launch_bounds__(256) void k_agg(
    const unsigned char* __restrict__ Gq, const unsigned short* __restrict__ Rb,
    const int* __restrict__ row_off, const int* __restrict__ deg,
    const float* __restrict__ deg_inv, const int* __restrict__ csr_src,
    unsigned short* __restrict__ outH) {
    const int wave = threadIdx.x >> 6;
    const int lane = threadIdx.x & 63;
    const int g = lane >> 3;        // node slot 0..7 within wave
    const int l = lane & 7;         // feature slice within node
    const int n = (blockIdx.x * 4 + wave) * 8 + g;
    const int start = row_off[n];
    const int d = deg[n];
    const float di = deg_inv[n];
    const int fo = l * 16;          // fp8 byte offset == bf16 element offset

    // wave-uniform max degree over the 8 groups (group id lives in lane bits 3..5)
    int dmax = d;
    dmax = max(dmax, __shfl_xor(dmax, 8, 64));
    dmax = max(dmax, __shfl_xor(dmax, 16, 64));
    dmax = max(dmax, __shfl_xor(dmax, 32, 64));

    // prefetch the R slice (all 64 lanes useful)
    const uint4 rv0 = *(const uint4*)&Rb[(size_t)n * HDIM + fo];
    const uint4 rv1 = *(const uint4*)&Rb[(size_t)n * HDIM + fo + 8];

    f32x2 acc2[8];
#pragma unroll
    for (int i = 0; i < 8; i++) acc2[i] = (f32x2){0.f, 0.f};

    // chunked edge-index prefetch: idxA = chunk c (iters c*8..c*8+7),
    // idxB = chunk c+1. Lane l of group g holds csr_src[start_g + c*8 + l].
    int idxA = (l < d) ? csr_src[start + l] * HDIM : 0;
    int idxB = (8 + l < d) ? csr_src[start + 8 + l] * HDIM : 0;

    uint4 cur = {0u, 0u, 0u, 0u};
    {
        const int off0 = __shfl(idxA, g << 3, 64);        // full-exec shfl
        if (0 < d) cur = *(const uint4*)&Gq[(size_t)(unsigned)off0 + fo];
    }
#define ACC16(Cv)                                                        \
    acc2[0] += __builtin_amdgcn_cvt_pk_f32_fp8((int)(Cv).x, false);      \
    acc2[1] += __builtin_amdgcn_cvt_pk_f32_fp8((int)(Cv).x, true);       \
    acc2[2] += __builtin_amdgcn_cvt_pk_f32_fp8((int)(Cv).y, false);      \
    acc2[3] += __builtin_amdgcn_cvt_pk_f32_fp8((int)(Cv).y, true);       \
    acc2[4] += __builtin_amdgcn_cvt_pk_f32_fp8((int)(Cv).z, false);      \
    acc2[5] += __builtin_amdgcn_cvt_pk_f32_fp8((int)(Cv).z, true);       \
    acc2[6] += __builtin_amdgcn_cvt_pk_f32_fp8((int)(Cv).w, false);      \
    acc2[7] += __builtin_amdgcn_cvt_pk_f32_fp8((int)(Cv).w, true);

    for (int i = 1; i < dmax; i++) {
        const int sl = i & 7;
        if (sl == 0) {               // wave-uniform chunk rotation
            idxA = idxB;
            const int j = i + 8 + l; // base of chunk c+2
            idxB = (j < d) ? csr_src[start + j] * HDIM : 0;
        }
        const int offn = __shfl(idxA, (g << 3) | sl, 64); // full-exec shfl
        uint4 nxt = {0u, 0u, 0u, 0u};
        if (i < d) nxt = *(const uint4*)&Gq[(size_t)(unsigned)offn + fo];
        // consume cur (vmcnt(1): nxt stays in flight)
        ACC16(cur);
        cur = nxt;
    }
    ACC16(cur);
#undef ACC16

    // epilogue: every lane scales its 16 features, adds R, relu, packs, stores
    const float r[16] = {bf_lo(rv0.x), bf_hi(rv0.x), bf_lo(rv0.y), bf_hi(rv0.y),
                         bf_lo(rv0.z), bf_hi(rv0.z), bf_lo(rv0.w), bf_hi(rv0.w),
                         bf_lo(rv1.x), bf_hi(rv1.x), bf_lo(rv1.y), bf_hi(rv1.y),
                         bf_lo(rv1.z), bf_hi(rv1.z), bf_lo(rv1.w), bf_hi(rv1.w)};
    unsigned short o[16];
#pragma unroll
    for (int i = 0; i < 8; i++) {
        o[2 * i]     = f2bf(fmaxf(acc2[i].x * di + r[2 * i], 0.f));
        o[2 * i + 1] = f2bf(fmaxf(acc2[i].y * di + r[2 * i + 1], 0.f));
    }
    uint4 p0, p1;
    p0.x = (unsigned int)o[0] | ((unsigned int)o[1] << 16);
    p0.y = (unsigned int)o[2] | ((unsigned int)o[3] << 16);
    p0.z = (unsigned int)o[4] | ((unsigned int)o[5] << 16);
    p0.w = (unsigned int)o[6] | ((unsigned int)o[7] << 16);
    p1.x = (unsigned int)o[8] | ((unsigned int)o[9] << 16);
    p1.y = (unsigned int)o[10] | ((unsigned int)o[11] << 16);
    p1.z = (unsigned int)o[12] | ((unsigned int)o[13] << 16);
    p1.w = (unsigned int)o[14] | ((unsigned int)o[15] << 16);
    *(uint4*)&outH[(size_t)n * HDIM + fo] = p0;
    *(uint4*)&outH[(size_t)n * HDIM + fo + 8] = p1;
}

// ---------------- logits GEMM, j-major output ----------------
// R2: same LDS double-buffer staging as k_gemm_dual (bf16 path).

__global__ __launch_bounds__(256) void k_gemm_logits(
    const unsigned short* __restrict__ A, const unsigned short* __restrict__ W,
    const float* __restrict__ bias, float* __restrict__ out) {
    __shared__ __align__(16) unsigned char smem[8192];
    const int tix  = threadIdx.x;
    const int wave = tix >> 6;
    const int lane = tix & 63;
    const int m16  = lane & 15;
    const int quad = lane >> 4;
    const int u0   = wave * 2;
    const int xk   = m16 & 7;

    bfrag wf[2][KCH];
    float bsj[2];
#pragma unroll
    for (int u = 0; u < 2; u++) {
        const int unit = u0 + u;
        const int j = (unit < 7 ? unit : 0) * 16 + m16;
#pragma unroll
        for (int c = 0; c < KCH; c++)
            wf[u][c] = *(const bfrag*)&W[(size_t)j * HDIM + c * 32 + quad * 8];
        bsj[u] = bias[j];
    }

    const int sw2 = (tix ^ ((tix >> 4) & 7)) << 4;
    const int ldsoff = wave << 10;

    int tile = blockIdx.x;
    {
        const unsigned char* g = (const unsigned char*)A + (size_t)tile * 4096;
        gload_lds16(g + sw2, smem + ldsoff);
    }
    __syncthreads();

    for (int buf = 0; tile < NTILES; tile += GEMM_BLOCKS, buf ^= 1) {
        const int tn = tile + GEMM_BLOCKS;
        const bool more = (tn < NTILES);
        if (more) {
            const unsigned char* g = (const unsigned char*)A + (size_t)tn * 4096;
            gload_lds16(g + sw2, smem + (buf ^ 1) * 4096 + ldsoff);
        }

        const unsigned char* B = smem + buf * 4096;
        bfrag hf[KCH];
#pragma unroll
        for (int c = 0; c < KCH; c++) {
            const int s = m16 * 16 + c * 4 + quad;
            hf[c] = *(const bfrag*)(B + ((s ^ xk) << 4));
        }

#pragma unroll
        for (int u = 0; u < 2; u++) {
            const int unit = u0 + u;
            if (unit >= 7) break;
            ffrag acc = {0.f, 0.f, 0.f, 0.f};
#pragma unroll
            for (int c = 0; c < KCH; c++)
                acc = __builtin_amdgcn_mfma_f32_16x16x32_bf16(hf[c], wf[u][c], acc, 0, 0, 0);
            const int j = unit * 16 + m16;
            if (j < NUM_CARDS) {
#pragma unroll
                for (int r = 0; r < 4; r++) {
                    const int node = tile * 16 + quad * 4 + r;
                    out[(size_t)node * NUM_CARDS + j] = acc[r] + bsj[u];
                }
            }
        }

        if (more) __syncthreads();
    }
}

// ---------------- launch ----------------

static inline size_t align_up(size_t x, size_t a) { return (x + a - 1) & ~(a - 1); }

extern "C" void kernel_launch(void* const* d_in, const int* in_sizes, int n_in,
                              void* d_out, int out_size, void* d_ws, size_t ws_size,
                              hipStream_t stream) {
    const float* x   = (const float*)d_in[0];
    const float* Wl1 = (const float*)d_in[1];
    const float* bl1 = (const float*)d_in[2];
    const float* Wr1 = (const float*)d_in[3];
    const float* br1 = (const float*)d_in[4];
    const float* Wl2 = (const float*)d_in[5];
    const float* bl2 = (const float*)d_in[6];
    const float* Wr2 = (const float*)d_in[7];
    const float* br2 = (const float*)d_in[8];
    const float* Wo  = (const float*)d_in[9];
    const float* bo  = (const float*)d_in[10];
    const int* edge  = (const int*)d_in[11];
    const int* cards = (const int*)d_in[12];
    float* logits = (float*)d_out;

    const int* e_src = edge;
    const int* e_dst = edge + N_EDGES;

    char* w = (char*)d_ws;
    size_t off = 0;
    int* bucket_cursor = (int*)(w + off); off = align_up(off + 256 * 4, 512);
    unsigned int* part = (unsigned int*)(w + off); off = align_up(off + (size_t)NB * MAXB * 4, 512);
    int* row_off = (int*)(w + off); off = align_up(off + N_NODES * 4, 512);
    int* deg_i   = (int*)(w + off); off = align_up(off + N_NODES * 4, 512);
    float* dinv  = (float*)(w + off); off = align_up(off + N_NODES * 4, 512);
    int* csr_src = (int*)(w + off); off = align_up(off + (size_t)NB * MAXB * 4, 512);
    unsigned char*  Gq   = (unsigned char*)(w + off);  off = align_up(off + (size_t)N_NODES * HDIM, 512);
    unsigned short* Rb   = (unsigned short*)(w + off); off = align_up(off + (size_t)N_NODES * HDIM * 2, 512);
    unsigned short* bufH = (unsigned short*)(w + off); off = align_up(off + (size_t)N_NODES * HDIM * 2, 512);
    unsigned short* W1   = (unsigned short*)(w + off); off = align_up(off + 256 * HDIM * 2, 512);
    unsigned short* W2   = (unsigned short*)(w + off); off = align_up(off + 256 * HDIM * 2, 512);
    unsigned short* Wob  = (unsigned short*)(w + off); off = align_up(off + 112 * HDIM * 2, 512);
    float* bias1  = (float*)(w + off); off = align_up(off + 256 * 4, 512);
    float* bias2  = (float*)(w + off); off = align_up(off + 256 * 4, 512);
    float* biaso  = (float*)(w + off); off = align_up(off + 112 * 4, 512);
    float* wcard1 = (float*)(w + off); off = align_up(off + 256 * 4, 512);
    (void)ws_size; (void)n_in; (void)in_sizes; (void)out_size;

    hipMemsetAsync(bucket_cursor, 0, 256 * 4, stream);
    k_prep_w<<<256, 128, 0, stream>>>(Wl1, Wr1, bl1, br1, Wl2, Wr2, bl2, br2, Wo, bo,
                                      W1, W2, Wob, bias1, bias2, biaso, wcard1);

    const int PBLK = (N_EDGES + PT - 1) / PT;   // 391
    k_partition<<<PBLK, 256, 0, stream>>>(e_src, e_dst, bucket_cursor, part);
    k_bucket<<<NB, 256, 0, stream>>>(part, bucket_cursor,
                                     row_off, deg_i, dinv, csr_src);

    // layer 1 (reads f32 x directly, converts in-register)
    k_gemm_dual<<<GEMM_BLOCKS, 256, 0, stream>>>(nullptr, x, cards, W1, bias1, wcard1, Gq, Rb, 1);
    k_agg<<<N_NODES / 32, 256, 0, stream>>>(Gq, Rb, row_off, deg_i, dinv, csr_src, bufH);
    // layer 2
    k_gemm_dual<<<GEMM_BLOCKS, 256, 0, stream>>>(bufH, nullptr, nullptr, W2, bias2, wcard1, Gq, Rb, 0);
    k_agg<<<N_NODES / 32, 256, 0, stream>>>(Gq, Rb, row_off, deg_i, dinv, csr_src, bufH);
    // output
    k_gemm_logits<<<GEMM_BLOCKS, 256, 0, stream>>>(bufH, Wob, biaso, logits);
}

// Round 4
// 313.424 us; speedup vs baseline: 1.0732x; 1.0126x over previous
//
#include <hip/hip_runtime.h>
#include <hip/hip_bf16.h>

#define N_NODES 100000
#define N_EDGES 1600000
#define HDIM    128
#define KCH     4                  // K chunks of 32 (K = 128)
#define NUM_CARDS 110
#define NTILES  (N_NODES / 16)     // 6250 exactly
#define GEMM_BLOCKS 1024

#define NB      196                // node buckets: dst >> 9
#define MAXB    10240              // slack per bucket (avg 8192)
#define PT      4096               // edges per partition block
#define PEPT    16                 // edges per thread in partition

typedef __attribute__((ext_vector_type(8))) short bfrag;   // 8 bf16 = 4 VGPRs
typedef __attribute__((ext_vector_type(4))) float ffrag;   // 4 f32 acc
typedef __attribute__((ext_vector_type(2))) float f32x2;

__device__ inline unsigned short f2bf(float f) {
    __hip_bfloat16 h = __float2bfloat16(f);
    unsigned short u; __builtin_memcpy(&u, &h, 2); return u;
}
__device__ inline float bf_lo(unsigned int u) {
    unsigned int v = u << 16; float f; __builtin_memcpy(&f, &v, 4); return f;
}
__device__ inline float bf_hi(unsigned int u) {
    unsigned int v = u & 0xffff0000u; float f; __builtin_memcpy(&f, &v, 4); return f;
}

// async global->LDS, 16B per lane; LDS dest = wave-uniform base + lane*16
__device__ inline void gload_lds16(const void* g, void* l) {
    __builtin_amdgcn_global_load_lds(
        (const __attribute__((address_space(1))) unsigned int*)g,
        (__attribute__((address_space(3))) unsigned int*)l, 16, 0, 0);
}

// ---------------- CSR build: bucketed counting sort ----------------
// pack: (dst & 511) << 17 | src   (src < 2^17)

__global__ __launch_bounds__(256) void k_partition(
    const int* __restrict__ src, const int* __restrict__ dst,
    int* __restrict__ bucket_cursor, unsigned int* __restrict__ part) {
    __shared__ int hist[NB];
    __shared__ int hcur[NB];
    const int t = threadIdx.x;
    const int base = blockIdx.x * PT;
    for (int i = t; i < NB; i += 256) hist[i] = 0;
    __syncthreads();
#pragma unroll
    for (int i = 0; i < PEPT; i++) {
        int e = base + i * 256 + t;
        if (e < N_EDGES) atomicAdd(&hist[dst[e] >> 9], 1);
    }
    __syncthreads();
    for (int b = t; b < NB; b += 256) {
        int h = hist[b];
        hcur[b] = h ? atomicAdd(&bucket_cursor[b], h) : 0;
    }
    __syncthreads();
#pragma unroll
    for (int i = 0; i < PEPT; i++) {
        int e = base + i * 256 + t;
        if (e < N_EDGES) {
            int d = dst[e];
            int b = d >> 9;
            int r = atomicAdd(&hcur[b], 1);
            if (r < MAXB)
                part[(size_t)b * MAXB + r] =
                    ((unsigned int)(d & 511) << 17) | (unsigned int)src[e];
        }
    }
}

// fixed-stride csr layout: bucket b owns csr_src[b*MAXB .. b*MAXB+cnt)
__global__ __launch_bounds__(256) void k_bucket(
    const unsigned int* __restrict__ part, const int* __restrict__ bucket_cursor,
    int* __restrict__ row_off, int* __restrict__ deg, float* __restrict__ deg_inv,
    int* __restrict__ csr_src) {
    __shared__ int degl[512];
    __shared__ int offl[512];
    __shared__ int curl[512];
    __shared__ int stmp[256];
    const int t = threadIdx.x;
    const int b = blockIdx.x;
    const int n0 = b << 9;
    const int nb = min(512, N_NODES - n0);
    const int cnt = min(bucket_cursor[b], MAXB);
    const int row0 = b * MAXB;
    const unsigned int* pb = &part[(size_t)b * MAXB];

    degl[t] = 0; degl[t + 256] = 0;
    __syncthreads();
    for (int i = t; i < cnt; i += 256)
        atomicAdd(&degl[pb[i] >> 17], 1);
    __syncthreads();
    const int a0 = degl[2 * t], a1 = degl[2 * t + 1];
    stmp[t] = a0 + a1;
    __syncthreads();
    for (int off = 1; off < 256; off <<= 1) {
        int x = (t >= off) ? stmp[t - off] : 0;
        __syncthreads();
        stmp[t] += x;
        __syncthreads();
    }
    const int excl = stmp[t] - (a0 + a1);
    offl[2 * t] = excl;          curl[2 * t] = excl;
    offl[2 * t + 1] = excl + a0; curl[2 * t + 1] = excl + a0;
    __syncthreads();
    for (int i = t; i < nb; i += 256) {
        int n = n0 + i;
        int d = degl[i];
        row_off[n] = row0 + offl[i];
        deg[n] = d;
        deg_inv[n] = (d > 0) ? 1.0f / (float)d : 0.0f;
    }
    for (int i = t; i < cnt; i += 256) {
        unsigned int pk = pb[i];
        int r = atomicAdd(&curl[pk >> 17], 1);
        csr_src[row0 + r] = (int)(pk & 0x1FFFFu);
    }
}

// ---------------- prep: weights -> bf16 concat layouts ----------------

__global__ void k_prep_w(const float* __restrict__ Wl1, const float* __restrict__ Wr1,
                         const float* __restrict__ bl1, const float* __restrict__ br1,
                         const float* __restrict__ Wl2, const float* __restrict__ Wr2,
                         const float* __restrict__ bl2, const float* __restrict__ br2,
                         const float* __restrict__ Wo,  const float* __restrict__ bo,
                         unsigned short* __restrict__ W1, unsigned short* __restrict__ W2,
                         unsigned short* __restrict__ Wob,
                         float* __restrict__ bias1, float* __restrict__ bias2,
                         float* __restrict__ biaso, float* __restrict__ wcard1) {
    const int j = blockIdx.x;   // 0..255
    const int k = threadIdx.x;  // 0..127
    const float* s1 = (j < 128) ? &Wl1[(size_t)j * 129] : &Wr1[(size_t)(j - 128) * 129];
    W1[(size_t)j * HDIM + k] = f2bf(s1[k]);
    const float* s2 = (j < 128) ? &Wl2[(size_t)j * HDIM] : &Wr2[(size_t)(j - 128) * HDIM];
    W2[(size_t)j * HDIM + k] = f2bf(s2[k]);
    if (j < 112)
        Wob[(size_t)j * HDIM + k] = (j < NUM_CARDS) ? f2bf(Wo[(size_t)j * HDIM + k])
                                                    : (unsigned short)0;
    if (k == 0) {
        wcard1[j] = s1[HDIM];
        bias1[j] = (j < 128) ? 0.f : (bl1[j - 128] + br1[j - 128]);
        bias2[j] = (j < 128) ? 0.f : (bl2[j - 128] + br2[j - 128]);
        if (j < 112) biaso[j] = (j < NUM_CARDS) ? bo[j] : 0.f;
    }
}

// ---------------- dual GEMM: Gq (fp8 e4m3) + Rb (bf16) ----------------
// R3: triple-buffered LDS staging with COUNTED vmcnt (T3/T4). Per iter:
// issue stage(t+1) first, then `s_waitcnt vmcnt(S)` (S = stage ops/wave),
// then raw s_barrier. In-order vmcnt retirement => S(t)+stores(t-1) retire,
// S(t+1) stays in flight across the barrier. Triple buffer because the
// stage(t+1) issue precedes the barrier while stragglers may still read
// buf(t-1). Tail iterations safe because K(stores) >= S follows each stage.

template <int L1>
__global__ __launch_bounds__(256) void k_gemm_dual(
    const unsigned short* __restrict__ Ab, const float* __restrict__ Af,
    const int* __restrict__ cards,
    const unsigned short* __restrict__ W,
    const float* __restrict__ bias, const float* __restrict__ wcard,
    unsigned char* __restrict__ Gq, unsigned short* __restrict__ Rb) {
    constexpr int BUFSZ = L1 ? 8192 : 4096;
    __shared__ __align__(16) unsigned char smem[3 * BUFSZ + 2048];
    float* bias_l = (float*)(smem + 3 * BUFSZ);
    float* wc_l   = (float*)(smem + 3 * BUFSZ + 1024);

    const int tix  = threadIdx.x;
    const int wave = tix >> 6;
    const int lane = tix & 63;
    const int m16  = lane & 15;
    const int quad = lane >> 4;
    const int u0   = wave * 4;
    const bool isG = (wave < 2);
    const int xk   = m16 & 7;

    // weights -> regs (64 VGPR)
    bfrag wf[4][KCH];
#pragma unroll
    for (int u = 0; u < 4; u++) {
        const int j = (u0 + u) * 16 + m16;
#pragma unroll
        for (int c = 0; c < KCH; c++)
            wf[u][c] = *(const bfrag*)&W[(size_t)j * HDIM + c * 32 + quad * 8];
    }

    bias_l[tix] = bias[tix];
    wc_l[tix]   = L1 ? wcard[tix] : 0.f;

    // per-lane swizzled staging source (rule #21: linear LDS dest,
    // inverse-swizzled global source, swizzled ds_read)
    const int sw = L1 ? ((tix ^ ((tix >> 5) & 7)) << 4)
                      : ((tix ^ ((tix >> 4) & 7)) << 4);
    const int ldsoff = wave << 10;   // wave * 1024 (64 lanes x 16B)

    int rawc = 0, rawc_n = 0;

#define STAGE_DUAL(T, BI)                                                     \
    do {                                                                      \
        unsigned char* dst_ = smem + (BI) * BUFSZ + ldsoff;                   \
        if (L1) {                                                             \
            rawc_n = cards[(T) * 16 + m16];                                   \
            const unsigned char* g_ =                                         \
                (const unsigned char*)Af + (size_t)(T) * 8192;                \
            gload_lds16(g_ + sw, dst_);                                       \
            gload_lds16(g_ + sw + 4096, dst_ + 4096);                         \
        } else {                                                              \
            const unsigned char* g_ =                                         \
                (const unsigned char*)Ab + (size_t)(T) * 4096;                \
            gload_lds16(g_ + sw, dst_);                                       \
        }                                                                     \
    } while (0)

    int tile = blockIdx.x;
    STAGE_DUAL(tile, 0);            // S(0)
    rawc = rawc_n;                  // tile0's cards value
    asm volatile("s_waitcnt lgkmcnt(0)" ::: "memory"); // bias/wc LDS visible

    int b = 0;
    for (; tile < NTILES; tile += GEMM_BLOCKS) {
        const int tn = tile + GEMM_BLOCKS;
        const float cv = L1 ? (float)rawc : 0.f;   // capture before restage
        if (tn < NTILES) {
            STAGE_DUAL(tn, (b == 2 ? 0 : b + 1));  // S(t+1), stays in flight
            rawc = rawc_n;
        }
        if (L1) asm volatile("s_waitcnt vmcnt(3)" ::: "memory");
        else    asm volatile("s_waitcnt vmcnt(1)" ::: "memory");
        __builtin_amdgcn_s_barrier();              // buf(t) staged for all waves
        __builtin_amdgcn_sched_barrier(0);

        // fragments from LDS (swizzled read addresses)
        const unsigned char* B = smem + b * BUFSZ;
        bfrag hf[KCH];
        if (L1) {
#pragma unroll
            for (int c = 0; c < KCH; c++) {
                const int s0 = m16 * 32 + c * 8 + quad * 2;
                const float4 p0 = *(const float4*)(B + (((s0    ) ^ xk) << 4));
                const float4 p1 = *(const float4*)(B + (((s0 + 1) ^ xk) << 4));
                bfrag h;
                h[0] = (short)f2bf(p0.x); h[1] = (short)f2bf(p0.y);
                h[2] = (short)f2bf(p0.z); h[3] = (short)f2bf(p0.w);
                h[4] = (short)f2bf(p1.x); h[5] = (short)f2bf(p1.y);
                h[6] = (short)f2bf(p1.z); h[7] = (short)f2bf(p1.w);
                hf[c] = h;
            }
        } else {
#pragma unroll
            for (int c = 0; c < KCH; c++) {
                const int s = m16 * 16 + c * 4 + quad;
                hf[c] = *(const bfrag*)(B + ((s ^ xk) << 4));
            }
        }

        // compute + store current tile
        const int node = tile * 16 + m16;
#pragma unroll
        for (int u = 0; u < 4; u++) {
            ffrag acc = {0.f, 0.f, 0.f, 0.f};
#pragma unroll
            for (int c = 0; c < KCH; c++)
                acc = __builtin_amdgcn_mfma_f32_16x16x32_bf16(wf[u][c], hf[c], acc, 0, 0, 0);
            const int jj0 = (u0 + u) * 16 + quad * 4;
            const float4 b0 = *(const float4*)&bias_l[jj0];
            const float4 w0 = *(const float4*)&wc_l[jj0];
            float v[4];
            v[0] = acc[0] + b0.x + cv * w0.x;
            v[1] = acc[1] + b0.y + cv * w0.y;
            v[2] = acc[2] + b0.z + cv * w0.z;
            v[3] = acc[3] + b0.w + cv * w0.w;
            if (isG) {
                int pk = __builtin_amdgcn_cvt_pk_fp8_f32(v[0], v[1], 0, false);
                pk = __builtin_amdgcn_cvt_pk_fp8_f32(v[2], v[3], pk, true);
                *(unsigned int*)&Gq[(size_t)node * HDIM + (u0 + u) * 16 + quad * 4] =
                    (unsigned int)pk;
            } else {
                unsigned short o[4];
#pragma unroll
                for (int r = 0; r < 4; r++) o[r] = f2bf(v[r]);
                uint2 p = {(unsigned int)o[0] | ((unsigned int)o[1] << 16),
                           (unsigned int)o[2] | ((unsigned int)o[3] << 16)};
                *(uint2*)&Rb[(size_t)node * HDIM + (u0 + u - 8) * 16 + quad * 4] = p;
            }
        }
        b = (b == 2 ? 0 : b + 1);
    }
#undef STAGE_DUAL
}

// ---------------- aggregate: h' = relu(mean(Gq[src]) + Rb) ----------------
// R3: depth-16 gather pipeline. All 4 index chunks (32 edges, covers all
// but ~3 waves) preloaded up front; 4 chunks fully unrolled in a
// load/consume interleave so 8-16 gathers stay in flight. Rare dmax>32
// takes a serial tail. 8 nodes/wave, 8 lanes/node, lane owns 16 fp8
// features privately (no cross-lane reduction).

__global__ __launch_bounds__(256) void k_agg(
    const unsigned char* __restrict__ Gq, const unsigned short* __restrict__ Rb,
    const int* __restrict__ row_off, const int* __restrict__ deg,
    const float* __restrict__ deg_inv, const int* __restrict__ csr_src,
    unsigned short* __restrict__ outH) {
    const int wave = threadIdx.x >> 6;
    const int lane = threadIdx.x & 63;
    const int g = lane >> 3;        // node slot 0..7 within wave
    const int l = lane & 7;         // feature slice within node
    const int n = (blockIdx.x * 4 + wave) * 8 + g;
    const int start = row_off[n];
    const int d = deg[n];
    const float di = deg_inv[n];
    const int fo = l * 16;          // fp8 byte offset == bf16 element offset

    // wave-uniform max degree over the 8 groups
    int dmax = d;
    dmax = max(dmax, __shfl_xor(dmax, 8, 64));
    dmax = max(dmax, __shfl_xor(dmax, 16, 64));
    dmax = max(dmax, __shfl_xor(dmax, 32, 64));

    // prefetch the R slice (all 64 lanes useful)
    const uint4 rv0 = *(const uint4*)&Rb[(size_t)n * HDIM + fo];
    const uint4 rv1 = *(const uint4*)&Rb[(size_t)n * HDIM + fo + 8];

    f32x2 acc2[8];
#pragma unroll
    for (int i = 0; i < 8; i++) acc2[i] = (f32x2){0.f, 0.f};

    // preload 4 index chunks (edges 0..31; lane l of group g holds edge c*8+l)
    const int i0 = (l      < d) ? csr_src[start + l     ] * HDIM : 0;
    const int i1 = (l + 8  < d) ? csr_src[start + l +  8] * HDIM : 0;
    const int i2 = (l + 16 < d) ? csr_src[start + l + 16] * HDIM : 0;
    const int i3 = (l + 24 < d) ? csr_src[start + l + 24] * HDIM : 0;

#define ACC16(Cv)                                                        \
    acc2[0] += __builtin_amdgcn_cvt_pk_f32_fp8((int)(Cv).x, false);      \
    acc2[1] += __builtin_amdgcn_cvt_pk_f32_fp8((int)(Cv).x, true);       \
    acc2[2] += __builtin_amdgcn_cvt_pk_f32_fp8((int)(Cv).y, false);      \
    acc2[3] += __builtin_amdgcn_cvt_pk_f32_fp8((int)(Cv).y, true);       \
    acc2[4] += __builtin_amdgcn_cvt_pk_f32_fp8((int)(Cv).z, false);      \
    acc2[5] += __builtin_amdgcn_cvt_pk_f32_fp8((int)(Cv).z, true);       \
    acc2[6] += __builtin_amdgcn_cvt_pk_f32_fp8((int)(Cv).w, false);      \
    acc2[7] += __builtin_amdgcn_cvt_pk_f32_fp8((int)(Cv).w, true);

#define LOADCHUNK(Q, IR, CB)                                                  \
    {                                                                         \
        _Pragma("unroll")                                                     \
        for (int k = 0; k < 8; k++) {                                         \
            const int off_ = __shfl((IR), (g << 3) | k, 64);                  \
            uint4 t_ = {0u, 0u, 0u, 0u};                                      \
            if ((CB) + k < d)                                                 \
                t_ = *(const uint4*)&Gq[(size_t)(unsigned)off_ + fo];         \
            Q[k] = t_;                                                        \
        }                                                                     \
    }
#define CONSUME(Q)                                                            \
    {                                                                         \
        _Pragma("unroll")                                                     \
        for (int k = 0; k < 8; k++) { ACC16(Q[k]); }                          \
    }

    uint4 qa[8], qb[8];
    const bool m1 = dmax > 8, m2 = dmax > 16, m3 = dmax > 24;

    LOADCHUNK(qa, i0, 0)
    if (m1) LOADCHUNK(qb, i1, 8)
    CONSUME(qa)                    // qb (and beyond) stay in flight
    if (m2) LOADCHUNK(qa, i2, 16)
    if (m1) CONSUME(qb)
    if (m3) LOADCHUNK(qb, i3, 24)
    if (m2) CONSUME(qa)
    if (m3) CONSUME(qb)

    if (dmax > 32) {               // rare (~3 waves in the whole graph)
        for (int c = 4; c * 8 < dmax; c++) {
            const int jj = c * 8 + l;
            const int ir = (jj < d) ? csr_src[start + jj] * HDIM : 0;
            LOADCHUNK(qa, ir, c * 8)
            CONSUME(qa)
        }
    }
#undef LOADCHUNK
#undef CONSUME
#undef ACC16

    // epilogue: every lane scales its 16 features, adds R, relu, packs, stores
    const float r[16] = {bf_lo(rv0.x), bf_hi(rv0.x), bf_lo(rv0.y), bf_hi(rv0.y),
                         bf_lo(rv0.z), bf_hi(rv0.z), bf_lo(rv0.w), bf_hi(rv0.w),
                         bf_lo(rv1.x), bf_hi(rv1.x), bf_lo(rv1.y), bf_hi(rv1.y),
                         bf_lo(rv1.z), bf_hi(rv1.z), bf_lo(rv1.w), bf_hi(rv1.w)};
    unsigned short o[16];
#pragma unroll
    for (int i = 0; i < 8; i++) {
        o[2 * i]     = f2bf(fmaxf(acc2[i].x * di + r[2 * i], 0.f));
        o[2 * i + 1] = f2bf(fmaxf(acc2[i].y * di + r[2 * i + 1], 0.f));
    }
    uint4 p0, p1;
    p0.x = (unsigned int)o[0] | ((unsigned int)o[1] << 16);
    p0.y = (unsigned int)o[2] | ((unsigned int)o[3] << 16);
    p0.z = (unsigned int)o[4] | ((unsigned int)o[5] << 16);
    p0.w = (unsigned int)o[6] | ((unsigned int)o[7] << 16);
    p1.x = (unsigned int)o[8] | ((unsigned int)o[9] << 16);
    p1.y = (unsigned int)o[10] | ((unsigned int)o[11] << 16);
    p1.z = (unsigned int)o[12] | ((unsigned int)o[13] << 16);
    p1.w = (unsigned int)o[14] | ((unsigned int)o[15] << 16);
    *(uint4*)&outH[(size_t)n * HDIM + fo] = p0;
    *(uint4*)&outH[(size_t)n * HDIM + fo + 8] = p1;
}

// ---------------- logits GEMM, j-major output ----------------
// R3: same triple-buffer + counted vmcnt (S=1) as k_gemm_dual.

__global__ __launch_bounds__(256) void k_gemm_logits(
    const unsigned short* __restrict__ A, const unsigned short* __restrict__ W,
    const float* __restrict__ bias, float* __restrict__ out) {
    __shared__ __align__(16) unsigned char smem[3 * 4096];
    const int tix  = threadIdx.x;
    const int wave = tix >> 6;
    const int lane = tix & 63;
    const int m16  = lane & 15;
    const int quad = lane >> 4;
    const int u0   = wave * 2;
    const int xk   = m16 & 7;

    bfrag wf[2][KCH];
    float bsj[2];
#pragma unroll
    for (int u = 0; u < 2; u++) {
        const int unit = u0 + u;
        const int j = (unit < 7 ? unit : 0) * 16 + m16;
#pragma unroll
        for (int c = 0; c < KCH; c++)
            wf[u][c] = *(const bfrag*)&W[(size_t)j * HDIM + c * 32 + quad * 8];
        bsj[u] = bias[j];
    }

    const int sw2 = (tix ^ ((tix >> 4) & 7)) << 4;
    const int ldsoff = wave << 10;

    int tile = blockIdx.x;
    {
        const unsigned char* g = (const unsigned char*)A + (size_t)tile * 4096;
        gload_lds16(g + sw2, smem + ldsoff);
    }

    int b = 0;
    for (; tile < NTILES; tile += GEMM_BLOCKS) {
        const int tn = tile + GEMM_BLOCKS;
        if (tn < NTILES) {
            const unsigned char* g = (const unsigned char*)A + (size_t)tn * 4096;
            gload_lds16(g + sw2, smem + (b == 2 ? 0 : b + 1) * 4096 + ldsoff);
        }
        asm volatile("s_waitcnt vmcnt(1)" ::: "memory");
        __builtin_amdgcn_s_barrier();
        __builtin_amdgcn_sched_barrier(0);

        const unsigned char* B = smem + b * 4096;
        bfrag hf[KCH];
#pragma unroll
        for (int c = 0; c < KCH; c++) {
            const int s = m16 * 16 + c * 4 + quad;
            hf[c] = *(const bfrag*)(B + ((s ^ xk) << 4));
        }

#pragma unroll
        for (int u = 0; u < 2; u++) {
            const int unit = u0 + u;
            if (unit >= 7) break;
            ffrag acc = {0.f, 0.f, 0.f, 0.f};
#pragma unroll
            for (int c = 0; c < KCH; c++)
                acc = __builtin_amdgcn_mfma_f32_16x16x32_bf16(hf[c], wf[u][c], acc, 0, 0, 0);
            const int j = unit * 16 + m16;
            if (j < NUM_CARDS) {
#pragma unroll
                for (int r = 0; r < 4; r++) {
                    const int node = tile * 16 + quad * 4 + r;
                    out[(size_t)node * NUM_CARDS + j] = acc[r] + bsj[u];
                }
            }
        }
        b = (b == 2 ? 0 : b + 1);
    }
}

// ---------------- launch ----------------

static inline size_t align_up(size_t x, size_t a) { return (x + a - 1) & ~(a - 1); }

extern "C" void kernel_launch(void* const* d_in, const int* in_sizes, int n_in,
                              void* d_out, int out_size, void* d_ws, size_t ws_size,
                              hipStream_t stream) {
    const float* x   = (const float*)d_in[0];
    const float* Wl1 = (const float*)d_in[1];
    const float* bl1 = (const float*)d_in[2];
    const float* Wr1 = (const float*)d_in[3];
    const float* br1 = (const float*)d_in[4];
    const float* Wl2 = (const float*)d_in[5];
    const float* bl2 = (const float*)d_in[6];
    const float* Wr2 = (const float*)d_in[7];
    const float* br2 = (const float*)d_in[8];
    const float* Wo  = (const float*)d_in[9];
    const float* bo  = (const float*)d_in[10];
    const int* edge  = (const int*)d_in[11];
    const int* cards = (const int*)d_in[12];
    float* logits = (float*)d_out;

    const int* e_src = edge;
    const int* e_dst = edge + N_EDGES;

    char* w = (char*)d_ws;
    size_t off = 0;
    int* bucket_cursor = (int*)(w + off); off = align_up(off + 256 * 4, 512);
    unsigned int* part = (unsigned int*)(w + off); off = align_up(off + (size_t)NB * MAXB * 4, 512);
    int* row_off = (int*)(w + off); off = align_up(off + N_NODES * 4, 512);
    int* deg_i   = (int*)(w + off); off = align_up(off + N_NODES * 4, 512);
    float* dinv  = (float*)(w + off); off = align_up(off + N_NODES * 4, 512);
    int* csr_src = (int*)(w + off); off = align_up(off + (size_t)NB * MAXB * 4, 512);
    unsigned char*  Gq   = (unsigned char*)(w + off);  off = align_up(off + (size_t)N_NODES * HDIM, 512);
    unsigned short* Rb   = (unsigned short*)(w + off); off = align_up(off + (size_t)N_NODES * HDIM * 2, 512);
    unsigned short* bufH = (unsigned short*)(w + off); off = align_up(off + (size_t)N_NODES * HDIM * 2, 512);
    unsigned short* W1   = (unsigned short*)(w + off); off = align_up(off + 256 * HDIM * 2, 512);
    unsigned short* W2   = (unsigned short*)(w + off); off = align_up(off + 256 * HDIM * 2, 512);
    unsigned short* Wob  = (unsigned short*)(w + off); off = align_up(off + 112 * HDIM * 2, 512);
    float* bias1  = (float*)(w + off); off = align_up(off + 256 * 4, 512);
    float* bias2  = (float*)(w + off); off = align_up(off + 256 * 4, 512);
    float* biaso  = (float*)(w + off); off = align_up(off + 112 * 4, 512);
    float* wcard1 = (float*)(w + off); off = align_up(off + 256 * 4, 512);
    (void)ws_size; (void)n_in; (void)in_sizes; (void)out_size;

    hipMemsetAsync(bucket_cursor, 0, 256 * 4, stream);
    k_prep_w<<<256, 128, 0, stream>>>(Wl1, Wr1, bl1, br1, Wl2, Wr2, bl2, br2, Wo, bo,
                                      W1, W2, Wob, bias1, bias2, biaso, wcard1);

    const int PBLK = (N_EDGES + PT - 1) / PT;   // 391
    k_partition<<<PBLK, 256, 0, stream>>>(e_src, e_dst, bucket_cursor, part);
    k_bucket<<<NB, 256, 0, stream>>>(part, bucket_cursor,
                                     row_off, deg_i, dinv, csr_src);

    // layer 1 (reads f32 x directly, converts in-register)
    k_gemm_dual<1><<<GEMM_BLOCKS, 256, 0, stream>>>(nullptr, x, cards, W1, bias1, wcard1, Gq, Rb);
    k_agg<<<N_NODES / 32, 256, 0, stream>>>(Gq, Rb, row_off, deg_i, dinv, csr_src, bufH);
    // layer 2
    k_gemm_dual<0><<<GEMM_BLOCKS, 256, 0, stream>>>(bufH, nullptr, nullptr, W2, bias2, wcard1, Gq, Rb);
    k_agg<<<N_NODES / 32, 256, 0, stream>>>(Gq, Rb, row_off, deg_i, dinv, csr_src, bufH);
    // output
    k_gemm_logits<<<GEMM_BLOCKS, 256, 0, stream>>>(bufH, Wob, biaso, logits);
}